// Round 13
// baseline (223.608 us; speedup 1.0000x reference)
//
#include <hip/hip_runtime.h>
#include <hip/hip_bf16.h>
#include <math.h>

// Problem constants (B=2, C=256, H=W=64, heads=8, hd=32, groups=32, hid=64)
#define NB 2
#define NC 256
#define NHEAD 8
#define HD 32
#define NPIX 4096
#define GEPS 1e-5f
#define NCHUNK 2          // j-split factor for attention (linear softmax => exact)
#define JLEN (NPIX / NCHUNK)

typedef short bf16x8 __attribute__((ext_vector_type(8)));
typedef float f32x4 __attribute__((ext_vector_type(4)));

typedef __attribute__((address_space(3))) unsigned int lds_u32;
typedef __attribute__((address_space(1))) const unsigned int glb_u32;

union U16x8 { uint4 u4; uint2 u2[2]; unsigned u32[4]; unsigned short us[8]; bf16x8 v; };

__device__ inline unsigned short tobf(float f) {  // round-to-nearest-even
  union { float f; unsigned u; } c; c.f = f;
  return (unsigned short)((c.u + 0x7FFFu + ((c.u >> 16) & 1u)) >> 16);
}
__device__ inline unsigned packtrunc(float lo, float hi) {  // truncating bf16 pack, 1 instr
  return __builtin_amdgcn_perm(__float_as_uint(hi), __float_as_uint(lo), 0x07060302u);
}
__device__ inline float geluf(float v) {
  return 0.5f * v * (1.f + erff(v * 0.70710678118654752f));
}

// Per-block dtype self-detection (bf16 vs fp32 x): wave-0 ballot + broadcast.
__device__ inline int detect_bf(const void* xraw) {
  __shared__ int flg;
  int t = threadIdx.x;
  if (t < 64) {
    unsigned short h = ((const unsigned short*)xraw)[2 * t];
    unsigned e = (h >> 7) & 0xFFu;
    int weird = (e < 113u || e > 140u) ? 1 : 0;
    unsigned long long m = __ballot(weird);
    if (t == 0) flg = (__popcll(m) > 16) ? 0 : 1;
  }
  __syncthreads();
  return flg;
}

struct ConvArgs { const void* src[13]; int off[14]; };

__device__ inline float ldsrc(const void* p, int idx, int bf) {
  if (bf) {
    unsigned v = ((const unsigned short*)p)[idx];
    return __uint_as_float(v << 16);
  }
  return ((const float*)p)[idx];
}

// ---------------------------------------------------------------------------
// Fused convert + prep + GN1 block-partials (self-detecting). Non-x blocks
// skip the reduction tree (block-uniform branch).
// ---------------------------------------------------------------------------
__global__ __launch_bounds__(256) void conv_prep_kernel(
    ConvArgs a, float* __restrict__ dstbase, int total,
    unsigned short* __restrict__ wqkv_b, unsigned short* __restrict__ wout_b,
    unsigned short* __restrict__ wm1_b, unsigned short* __restrict__ wm2_b,
    float* __restrict__ qscale, float* __restrict__ part1p) {
  int bf = detect_bf(a.src[0]);
  int blk = blockIdx.x, t = threadIdx.x;
  int i = blk * 256 + t;
  float val = 0.f;
  if (i < total) {
    int s = 0;
    while (i >= a.off[s + 1]) ++s;
    val = ldsrc(a.src[s], i - a.off[s], bf);
    dstbase[i] = val;
  }
  // GN1 partials (x = segment 0, exactly blocks 0..8191)
  if (blk < 8192) {
    __shared__ float rs[256], rq[256];
    rs[t] = val;
    rq[t] = val * val;
    __syncthreads();
    for (int o = 128; o > 0; o >>= 1) {
      if (t < o) { rs[t] += rs[t + o]; rq[t] += rq[t + o]; }
      __syncthreads();
    }
    if (t == 0) { part1p[blk * 2] = rs[0]; part1p[blk * 2 + 1] = rq[0]; }
  }
  // prep (reads raw sources)
  if (i < 196608) wqkv_b[i] = tobf(ldsrc(a.src[1], i, bf));
  else if (i < 262144) wout_b[i - 196608] = tobf(ldsrc(a.src[2], i - 196608, bf));
  else if (i < 278528) wm1_b[i - 262144] = tobf(ldsrc(a.src[9], i - 262144, bf));
  else if (i < 294912) wm2_b[i - 278528] = tobf(ldsrc(a.src[11], i - 278528, bf));
  if (i < 768) {
    if (i < 256) {
      float tc = fminf(fmaxf(ldsrc(a.src[4], i >> 5, bf), 1e-4f), 10.f);
      qscale[i] = tc * 1.4426950408889634f;
    } else qscale[i] = 1.0f;
  }
}

// ---------------------------------------------------------------------------
// QKV mega-kernel: GN1 finish -> normalize tile -> K=256 GEMM -> q/k/v
// native layouts (unchanged, proven).
// ---------------------------------------------------------------------------
__global__ __launch_bounds__(256) void qkv_fused_kernel(
    const float* __restrict__ x_f, const float* __restrict__ part1p,
    const float* __restrict__ g1, const float* __restrict__ be1,
    const unsigned short* __restrict__ W, const float* __restrict__ qscale,
    unsigned short* __restrict__ qn, unsigned short* __restrict__ kn,
    unsigned short* __restrict__ vs) {
  int t = threadIdx.x;
  int w = t >> 6, lane = t & 63, l16 = lane & 15, quad = lane >> 4;
  int p0 = blockIdx.x * 16;
  int b = p0 >> 12;
  __shared__ float red[32][8][2];
  __shared__ float sm[32], si[32];
  {
    int g = t >> 3, seg = t & 7;
    float s = 0.f, s2 = 0.f;
    const float* pp = part1p + ((size_t)(b * 32 + g) * 128 + seg * 16) * 2;
#pragma unroll
    for (int k = 0; k < 16; ++k) { s += pp[k * 2]; s2 += pp[k * 2 + 1]; }
    red[g][seg][0] = s; red[g][seg][1] = s2;
  }
  __syncthreads();
  if (t < 32) {
    float s = 0.f, s2 = 0.f;
#pragma unroll
    for (int k = 0; k < 8; ++k) { s += red[t][k][0]; s2 += red[t][k][1]; }
    float mean = s * (1.f / 32768.f);
    float var = s2 * (1.f / 32768.f) - mean * mean;
    sm[t] = mean; si[t] = rsqrtf(var + GEPS);
  }
  __syncthreads();
  __shared__ unsigned short Ys[16][264];
  {
    int p = t & 15, cg = t >> 4;
    int n = (p0 & 4095) + p;
    const float* src = x_f + ((size_t)b * NC + cg * 16) * NPIX + n;
    U16x8 lo, hi;
#pragma unroll
    for (int cc = 0; cc < 16; ++cc) {
      int c = cg * 16 + cc;
      int g = c >> 3;
      float gg = g1[c] * si[g];
      float vv = (src[(size_t)cc * NPIX] - sm[g]) * gg + be1[c];
      if (cc < 8) lo.us[cc] = tobf(vv); else hi.us[cc - 8] = tobf(vv);
    }
    *(uint4*)&Ys[p][cg * 16] = lo.u4;
    *(uint4*)&Ys[p][cg * 16 + 8] = hi.u4;
  }
  __syncthreads();
  int ob = blockIdx.y * 384 + w * 96;
  f32x4 acc[6] = {};
#pragma unroll
  for (int k0 = 0; k0 < 256; k0 += 32) {
    U16x8 bfr; bfr.u4 = *(const uint4*)&Ys[l16][k0 + quad * 8];
#pragma unroll
    for (int ot = 0; ot < 6; ++ot) {
      U16x8 af;
      af.u4 = *(const uint4*)(W + (size_t)(ob + ot * 16 + l16) * 256 + k0 + quad * 8);
      acc[ot] = __builtin_amdgcn_mfma_f32_16x16x32_bf16(af.v, bfr.v, acc[ot], 0, 0, 0);
    }
  }
  int n = (p0 & 4095) + l16;
#pragma unroll
  for (int ot = 0; ot < 6; ++ot) {
    int oc = ob + ot * 16 + quad * 4;
    float v[4];
#pragma unroll
    for (int r = 0; r < 4; ++r) v[r] = acc[ot][r] * qscale[oc + r];
    int sec = oc >> 8;
    int c = oc & 255;
    if (sec < 2) {
      int hh = c >> 5, d = c & 31;
      unsigned short* base = sec == 0 ? qn : kn;
      uint2 pk;
      pk.x = (unsigned)tobf(v[0]) | ((unsigned)tobf(v[1]) << 16);
      pk.y = (unsigned)tobf(v[2]) | ((unsigned)tobf(v[3]) << 16);
      *(uint2*)(base + ((size_t)(b * NHEAD + hh) * NPIX + n) * HD + d) = pk;
    } else {
#pragma unroll
      for (int r = 0; r < 4; ++r)
        vs[((size_t)(b * NC + c + r)) * NPIX + n] = tobf(v[r]);
    }
  }
}

// ---------------------------------------------------------------------------
// MFMA flash attention v9 (round-11 PROVEN, restored verbatim): cooperative
// DMA staging, 2 barriers/iter, 128-query blocks (512 thr / 8 waves). Waves
// 0-3 stage the shared K tile, waves 4-7 the V tile; source-side swizzles;
// NO register global loads in the loop. The r12 ping-pong (1 barrier/iter)
// raced -> inf P -> NaN; single-buffer DMA->barrier->compute is the safe
// structure at HIP level (barrier drain is structural, m97 notes).
// ---------------------------------------------------------------------------
__global__ __launch_bounds__(512) void attn9_kernel(
    const unsigned short* __restrict__ qn, const unsigned short* __restrict__ kn,
    const unsigned short* __restrict__ vs, float* __restrict__ pO,
    float* __restrict__ pl) {
  int bx = blockIdx.x;
  int iblk = bx & 31, chunk = bx >> 5;
  int i0 = iblk * 128;
  int jbase = chunk * JLEN;
  int h = blockIdx.y, b = blockIdx.z;
  int bh = b * NHEAD + h;
  int t = threadIdx.x;
  int w = t >> 6, lane = t & 63, l16 = lane & 15, quad = lane >> 4;

  __shared__ unsigned short Kt[2048];      // [64 j][4 p][8] swizzled
  __shared__ unsigned short Vt[2048];      // [32 d][8 p][8] swizzled
  __shared__ unsigned short Pl[8][16][72];

  U16x8 qf;
  qf.u4 = *(const uint4*)(qn + ((size_t)bh * NPIX + i0 + w * 16 + l16) * HD + quad * 8);
  U16x8 ones;
#pragma unroll
  for (int j = 0; j < 8; ++j) ones.us[j] = 0x3F80;

  // Staging assignment: waves 0-3 -> K (16 rows each), waves 4-7 -> V (8 rows).
  const unsigned short* gp;
  lds_u32* dst;
  if (w < 4) {
    int kj = (w << 4) + (lane >> 2);
    int kg = (lane & 3) ^ ((kj >> 1) & 3);
    gp = kn + ((size_t)bh * NPIX + jbase + kj) * HD + kg * 8;
    dst = (lds_u32*)&Kt[w * 512];
  } else {
    int vd = ((w - 4) << 3) + (lane >> 3);
    int vg = (lane & 7) ^ (vd & 7);
    gp = vs + ((size_t)(b * NC + h * HD + vd)) * NPIX + jbase + vg * 8;
    dst = (lds_u32*)&Vt[(w - 4) * 512];
  }
  int gstep = (w < 4) ? 64 * HD : 64;

  f32x4 o0 = {0.f, 0.f, 0.f, 0.f}, o1 = {0.f, 0.f, 0.f, 0.f};
  f32x4 lacc = {0.f, 0.f, 0.f, 0.f};
  const f32x4 zf = {0.f, 0.f, 0.f, 0.f};

  int sp = (quad ^ ((l16 >> 1) & 3)) * 8;
  for (int jt = 0; jt < JLEN; jt += 64) {
    __builtin_amdgcn_global_load_lds((glb_u32*)gp, dst, 16, 0, 0);
    gp += gstep;
    __syncthreads();   // drains DMA (vmcnt0) + all waves staged
    f32x4 st[4];
#pragma unroll
    for (int jj = 0; jj < 4; ++jj) {
      U16x8 kf; kf.u4 = *(const uint4*)&Kt[(jj * 16 + l16) * 32 + sp];
      st[jj] = __builtin_amdgcn_mfma_f32_16x16x32_bf16(kf.v, qf.v, zf, 0, 0, 0);
    }
#pragma unroll
    for (int jj = 0; jj < 4; ++jj) {
      uint2 pk;
      pk.x = packtrunc(__builtin_amdgcn_exp2f(st[jj][0]), __builtin_amdgcn_exp2f(st[jj][1]));
      pk.y = packtrunc(__builtin_amdgcn_exp2f(st[jj][2]), __builtin_amdgcn_exp2f(st[jj][3]));
      *(uint2*)&Pl[w][l16][jj * 16 + quad * 4] = pk;
    }
#pragma unroll
    for (int ks = 0; ks < 2; ++ks) {
      U16x8 pb; pb.u4 = *(const uint4*)&Pl[w][l16][ks * 32 + quad * 8];
      int vp = ((ks * 4 + quad) ^ (l16 & 7)) * 8;
      U16x8 va; va.u4 = *(const uint4*)&Vt[l16 * 64 + vp];
      U16x8 vb2; vb2.u4 = *(const uint4*)&Vt[(16 + l16) * 64 + vp];
      o0 = __builtin_amdgcn_mfma_f32_16x16x32_bf16(va.v, pb.v, o0, 0, 0, 0);
      o1 = __builtin_amdgcn_mfma_f32_16x16x32_bf16(vb2.v, pb.v, o1, 0, 0, 0);
      lacc = __builtin_amdgcn_mfma_f32_16x16x32_bf16(ones.v, pb.v, lacc, 0, 0, 0);
    }
    __syncthreads();   // all waves done reading Kt/Vt before next DMA
  }

  // Partial store: block covers two 64-pixel groups; wout layout unchanged.
  int pr = bh * 64 + iblk * 2 + (w >> 2);
  float* ob = pO + ((size_t)chunk * 1024 + pr) * 2048;
  int icol = (w & 3) * 16 + l16;
#pragma unroll
  for (int r = 0; r < 4; ++r) {
    ob[(quad * 4 + r) * 64 + icol] = o0[r];
    ob[(16 + quad * 4 + r) * 64 + icol] = o1[r];
  }
  if (quad == 0)
    pl[((size_t)chunk * 1024 + pr) * 64 + icol] = lacc[0];
}

// ---------------------------------------------------------------------------
// wout GEMM with INLINE combine, channel-split for occupancy (gridDim.y=2,
// 2 ot per block = 128 output channels; 1024 blocks = 4/CU). B-frag built
// from pO chunk-sum * (1/l[head]); + bias + residual -> xres fp32
// channel-major, AND per-block GN2 partials (writer mapping verified:
// group g = half*16 + ww*4 + ot*2 + qp, bijective over the block's span).
// ---------------------------------------------------------------------------
__global__ __launch_bounds__(256) void wout_kernel(
    const unsigned short* __restrict__ W, const float* __restrict__ pO,
    const float* __restrict__ pl, const float* __restrict__ bias,
    const float* __restrict__ res, float* __restrict__ xres,
    float* __restrict__ part2p) {
  int t = threadIdx.x;
  int w = t >> 6, lane = t & 63, l16 = lane & 15, quad = lane >> 4;
  int p = blockIdx.x * 16 + l16;
  int half = blockIdx.y;
  int b = p >> 12, n = p & 4095;
  int i = p & 63, iblk = (p >> 6) & 63;
  int ob = half * 128 + w * 32;
  float rinv8[8];
#pragma unroll
  for (int hh = 0; hh < 8; ++hh) {
    size_t pr = (size_t)(b * NHEAD + hh) * 64 + iblk;
    float l = pl[pr * 64 + i] + pl[(1024 + pr) * 64 + i];
    rinv8[hh] = 1.f / l;
  }
  f32x4 acc[2] = {};
#pragma unroll
  for (int k0 = 0; k0 < 256; k0 += 32) {
    int hh = k0 >> 5;
    const float* q0 = pO + ((size_t)(b * NHEAD + hh) * 64 + iblk) * 2048 + quad * 8 * 64 + i;
    const float* q1 = q0 + (size_t)1024 * 2048;
    float rv = rinv8[hh];
    U16x8 bfr;
#pragma unroll
    for (int u = 0; u < 4; ++u) {
      float va = (q0[(2 * u) * 64] + q1[(2 * u) * 64]) * rv;
      float vb = (q0[(2 * u + 1) * 64] + q1[(2 * u + 1) * 64]) * rv;
      bfr.u32[u] = packtrunc(va, vb);
    }
#pragma unroll
    for (int ot = 0; ot < 2; ++ot) {
      U16x8 af;
      af.u4 = *(const uint4*)(W + (size_t)(ob + ot * 16 + l16) * 256 + k0 + quad * 8);
      acc[ot] = __builtin_amdgcn_mfma_f32_16x16x32_bf16(af.v, bfr.v, acc[ot], 0, 0, 0);
    }
  }
  __shared__ float sb[256][2][2];
#pragma unroll
  for (int ot = 0; ot < 2; ++ot) {
    int oc = ob + ot * 16 + quad * 4;
    float s = 0.f, s2 = 0.f;
#pragma unroll
    for (int r = 0; r < 4; ++r) {
      size_t oidx = ((size_t)(b * NC + oc + r)) * NPIX + n;
      float vv = acc[ot][r] + bias[oc + r] + res[oidx];
      xres[oidx] = vv;
      s += vv; s2 += vv * vv;
    }
    sb[t][ot][0] = s; sb[t][ot][1] = s2;
  }
  __syncthreads();
  if (t < 16) {
    int ww = t >> 2, ot = (t >> 1) & 1, qp = t & 1;
    float s = 0.f, s2 = 0.f;
#pragma unroll
    for (int q = 2 * qp; q < 2 * qp + 2; ++q)
      for (int l = 0; l < 16; ++l) {
        int tt = ww * 64 + q * 16 + l;
        s += sb[tt][ot][0]; s2 += sb[tt][ot][1];
      }
    int g = half * 16 + ww * 4 + ot * 2 + qp;
    size_t idx = ((size_t)(b * 32 + g) * 256 + (blockIdx.x & 255)) * 2;
    part2p[idx] = s; part2p[idx + 1] = s2;
  }
}

// ---------------------------------------------------------------------------
// MLP mega-kernel (unchanged, proven).
// ---------------------------------------------------------------------------
__global__ __launch_bounds__(256) void mlp_fused_kernel(
    const void* __restrict__ xraw, const float* __restrict__ xres,
    const float* __restrict__ part2p, const float* __restrict__ g2,
    const float* __restrict__ be2, const unsigned short* __restrict__ W1,
    const float* __restrict__ b1, const unsigned short* __restrict__ W2,
    const float* __restrict__ b2, void* __restrict__ dout) {
  int wbf = detect_bf(xraw);
  int t = threadIdx.x;
  int w = t >> 6, lane = t & 63, l16 = lane & 15, quad = lane >> 4;
  int p0 = blockIdx.x * 16;
  int b = p0 >> 12;
  __shared__ float red[32][8][2];
  __shared__ float sm[32], si[32];
  {
    int g = t >> 3, seg = t & 7;
    float s = 0.f, s2 = 0.f;
    const float* pp = part2p + ((size_t)(b * 32 + g) * 256 + seg * 32) * 2;
#pragma unroll
    for (int k = 0; k < 32; ++k) { s += pp[k * 2]; s2 += pp[k * 2 + 1]; }
    red[g][seg][0] = s; red[g][seg][1] = s2;
  }
  __syncthreads();
  if (t < 32) {
    float s = 0.f, s2 = 0.f;
#pragma unroll
    for (int k = 0; k < 8; ++k) { s += red[t][k][0]; s2 += red[t][k][1]; }
    float mean = s * (1.f / 32768.f);
    float var = s2 * (1.f / 32768.f) - mean * mean;
    sm[t] = mean; si[t] = rsqrtf(var + GEPS);
  }
  __syncthreads();
  __shared__ float Xs[16][261];
  __shared__ unsigned short Ys[16][264];
  {
    int p = t & 15, cg = t >> 4;
    int n = (p0 & 4095) + p;
    const float* src = xres + ((size_t)b * NC + cg * 16) * NPIX + n;
    U16x8 lo, hi;
#pragma unroll
    for (int cc = 0; cc < 16; ++cc) {
      int c = cg * 16 + cc;
      int g = c >> 3;
      float v = src[(size_t)cc * NPIX];
      Xs[p][c] = v;
      float yv = (v - sm[g]) * (g2[c] * si[g]) + be2[c];
      if (cc < 8) lo.us[cc] = tobf(yv); else hi.us[cc - 8] = tobf(yv);
    }
    *(uint4*)&Ys[p][cg * 16] = lo.u4;
    *(uint4*)&Ys[p][cg * 16 + 8] = hi.u4;
  }
  __syncthreads();
  f32x4 a1 = {0.f, 0.f, 0.f, 0.f};
#pragma unroll
  for (int k0 = 0; k0 < 256; k0 += 32) {
    U16x8 bfr; bfr.u4 = *(const uint4*)&Ys[l16][k0 + quad * 8];
    U16x8 af;
    af.u4 = *(const uint4*)(W1 + (size_t)(w * 16 + l16) * 256 + k0 + quad * 8);
    a1 = __builtin_amdgcn_mfma_f32_16x16x32_bf16(af.v, bfr.v, a1, 0, 0, 0);
  }
  __shared__ unsigned short Hs[16][72];
  {
    int oc = w * 16 + quad * 4;
    float h0 = geluf(a1[0] + b1[oc]),     h1 = geluf(a1[1] + b1[oc + 1]);
    float h2 = geluf(a1[2] + b1[oc + 2]), h3 = geluf(a1[3] + b1[oc + 3]);
    uint2 pk;
    pk.x = (unsigned)tobf(h0) | ((unsigned)tobf(h1) << 16);
    pk.y = (unsigned)tobf(h2) | ((unsigned)tobf(h3) << 16);
    *(uint2*)&Hs[l16][oc] = pk;
  }
  __syncthreads();
  f32x4 a2[4] = {};
#pragma unroll
  for (int k0 = 0; k0 < 64; k0 += 32) {
    U16x8 bfr; bfr.u4 = *(const uint4*)&Hs[l16][k0 + quad * 8];
#pragma unroll
    for (int ot = 0; ot < 4; ++ot) {
      U16x8 af;
      af.u4 = *(const uint4*)(W2 + (size_t)(w * 64 + ot * 16 + l16) * 64 + k0 + quad * 8);
      a2[ot] = __builtin_amdgcn_mfma_f32_16x16x32_bf16(af.v, bfr.v, a2[ot], 0, 0, 0);
    }
  }
  int n = (p0 & 4095) + l16;
#pragma unroll
  for (int ot = 0; ot < 4; ++ot) {
    int oc = w * 64 + ot * 16 + quad * 4;
#pragma unroll
    for (int r = 0; r < 4; ++r) {
      float v = a2[ot][r] + b2[oc + r] + Xs[l16][oc + r];
      size_t oidx = ((size_t)(b * NC + oc + r)) * NPIX + n;
      if (wbf) ((__hip_bfloat16*)dout)[oidx] = __float2bfloat16(v);
      else ((float*)dout)[oidx] = v;
    }
  }
}

// ---------------------------------------------------------------------------
// Launch pipeline: 5 kernels.
// ---------------------------------------------------------------------------
extern "C" void kernel_launch(void* const* d_in, const int* in_sizes, int n_in,
                              void* d_out, int out_size, void* d_ws, size_t ws_size,
                              hipStream_t stream) {
  float* ws = (float*)d_ws;
  size_t off = 16;
  float* x_f    = ws + off; off += (size_t)NB * NC * NPIX;
  float* wqkv_f = ws + off; off += 768 * 256;
  float* wout_f = ws + off; off += 256 * 256;
  float* bout_f = ws + off; off += 256;
  float* temp_f = ws + off; off += 8;
  float* g1_f   = ws + off; off += 256;
  float* be1_f  = ws + off; off += 256;
  float* g2_f   = ws + off; off += 256;
  float* be2_f  = ws + off; off += 256;
  float* wm1_f  = ws + off; off += 64 * 256;
  float* bm1_f  = ws + off; off += 64;
  float* wm2_f  = ws + off; off += 256 * 64;
  float* bm2_f  = ws + off; off += 256;
  float* xres   = ws + off; off += (size_t)NB * NC * NPIX;
  unsigned short* qn     = (unsigned short*)(ws + off); off += 1048576;  // [16][4096][32]
  unsigned short* kn     = (unsigned short*)(ws + off); off += 1048576;  // [16][4096][32]
  unsigned short* vs     = (unsigned short*)(ws + off); off += 1048576;  // [2][256][4096]
  unsigned short* wqkv_b = (unsigned short*)(ws + off); off += 98304;
  unsigned short* wout_b = (unsigned short*)(ws + off); off += 32768;
  unsigned short* wm1_b  = (unsigned short*)(ws + off); off += 8192;
  unsigned short* wm2_b  = (unsigned short*)(ws + off); off += 8192;
  float* qscale = ws + off; off += 768;
  float* part1p = ws + off; off += 16384;   // [8192][2] GN1 block partials
  float* part2p = ws + off; off += 65536;   // [128 bg][256 blk][2] GN2 partials
  float* pO     = ws + off; off += (size_t)NCHUNK * 1024 * 2048;
  float* plb    = ws + off; off += (size_t)NCHUNK * 1024 * 64;
  (void)wqkv_f; (void)wout_f; (void)wm1_f; (void)wm2_f; (void)temp_f; (void)bm1_f;

  ConvArgs ca;
  int acc = 0;
  for (int i = 0; i < 13; ++i) {
    ca.src[i] = d_in[i];
    ca.off[i] = acc;
    acc += (i < n_in) ? in_sizes[i] : 0;
  }
  ca.off[13] = acc;
  conv_prep_kernel<<<(acc + 255) / 256, 256, 0, stream>>>(
      ca, x_f, acc, wqkv_b, wout_b, wm1_b, wm2_b, qscale, part1p);

  qkv_fused_kernel<<<dim3(512, 2), 256, 0, stream>>>(
      x_f, part1p, g1_f, be1_f, wqkv_b, qscale, qn, kn, vs);

  attn9_kernel<<<dim3(32 * NCHUNK, NHEAD, NB), 512, 0, stream>>>(qn, kn, vs, pO, plb);

  wout_kernel<<<dim3(512, 2), 256, 0, stream>>>(wout_b, pO, plb, bout_f, x_f, xres, part2p);

  mlp_fused_kernel<<<512, 256, 0, stream>>>(
      d_in[0], xres, part2p, g2_f, be2_f, wm1_b, bm1_f, wm2_b, bm2_f, d_out);
}

// Round 14
// 213.339 us; speedup vs baseline: 1.0481x; 1.0481x over previous
//
#include <hip/hip_runtime.h>
#include <hip/hip_bf16.h>
#include <math.h>

// Problem constants (B=2, C=256, H=W=64, heads=8, hd=32, groups=32, hid=64)
#define NB 2
#define NC 256
#define NHEAD 8
#define HD 32
#define NPIX 4096
#define GEPS 1e-5f
#define NCHUNK 2          // j-split factor for attention (linear softmax => exact)
#define JLEN (NPIX / NCHUNK)

typedef short bf16x8 __attribute__((ext_vector_type(8)));
typedef float f32x4 __attribute__((ext_vector_type(4)));

typedef __attribute__((address_space(3))) unsigned int lds_u32;
typedef __attribute__((address_space(1))) const unsigned int glb_u32;

union U16x8 { uint4 u4; uint2 u2[2]; unsigned u32[4]; unsigned short us[8]; bf16x8 v; };

__device__ inline unsigned short tobf(float f) {  // round-to-nearest-even
  union { float f; unsigned u; } c; c.f = f;
  return (unsigned short)((c.u + 0x7FFFu + ((c.u >> 16) & 1u)) >> 16);
}
__device__ inline unsigned packtrunc(float lo, float hi) {  // truncating bf16 pack, 1 instr
  return __builtin_amdgcn_perm(__float_as_uint(hi), __float_as_uint(lo), 0x07060302u);
}
__device__ inline float geluf(float v) {
  return 0.5f * v * (1.f + erff(v * 0.70710678118654752f));
}

// Per-block dtype self-detection (bf16 vs fp32 x): wave-0 ballot + broadcast.
__device__ inline int detect_bf(const void* xraw) {
  __shared__ int flg;
  int t = threadIdx.x;
  if (t < 64) {
    unsigned short h = ((const unsigned short*)xraw)[2 * t];
    unsigned e = (h >> 7) & 0xFFu;
    int weird = (e < 113u || e > 140u) ? 1 : 0;
    unsigned long long m = __ballot(weird);
    if (t == 0) flg = (__popcll(m) > 16) ? 0 : 1;
  }
  __syncthreads();
  return flg;
}

struct ConvArgs { const void* src[13]; int off[14]; };

__device__ inline float ldsrc(const void* p, int idx, int bf) {
  if (bf) {
    unsigned v = ((const unsigned short*)p)[idx];
    return __uint_as_float(v << 16);
  }
  return ((const float*)p)[idx];
}

// ---------------------------------------------------------------------------
// Fused convert + prep + GN1 block-partials (self-detecting). Non-x blocks
// skip the reduction tree (block-uniform branch).
// ---------------------------------------------------------------------------
__global__ __launch_bounds__(256) void conv_prep_kernel(
    ConvArgs a, float* __restrict__ dstbase, int total,
    unsigned short* __restrict__ wqkv_b, unsigned short* __restrict__ wout_b,
    unsigned short* __restrict__ wm1_b, unsigned short* __restrict__ wm2_b,
    float* __restrict__ qscale, float* __restrict__ part1p) {
  int bf = detect_bf(a.src[0]);
  int blk = blockIdx.x, t = threadIdx.x;
  int i = blk * 256 + t;
  float val = 0.f;
  if (i < total) {
    int s = 0;
    while (i >= a.off[s + 1]) ++s;
    val = ldsrc(a.src[s], i - a.off[s], bf);
    dstbase[i] = val;
  }
  // GN1 partials (x = segment 0, exactly blocks 0..8191)
  if (blk < 8192) {
    __shared__ float rs[256], rq[256];
    rs[t] = val;
    rq[t] = val * val;
    __syncthreads();
    for (int o = 128; o > 0; o >>= 1) {
      if (t < o) { rs[t] += rs[t + o]; rq[t] += rq[t + o]; }
      __syncthreads();
    }
    if (t == 0) { part1p[blk * 2] = rs[0]; part1p[blk * 2 + 1] = rq[0]; }
  }
  // prep (reads raw sources)
  if (i < 196608) wqkv_b[i] = tobf(ldsrc(a.src[1], i, bf));
  else if (i < 262144) wout_b[i - 196608] = tobf(ldsrc(a.src[2], i - 196608, bf));
  else if (i < 278528) wm1_b[i - 262144] = tobf(ldsrc(a.src[9], i - 262144, bf));
  else if (i < 294912) wm2_b[i - 278528] = tobf(ldsrc(a.src[11], i - 278528, bf));
  if (i < 768) {
    if (i < 256) {
      float tc = fminf(fmaxf(ldsrc(a.src[4], i >> 5, bf), 1e-4f), 10.f);
      qscale[i] = tc * 1.4426950408889634f;
    } else qscale[i] = 1.0f;
  }
}

// ---------------------------------------------------------------------------
// QKV mega-kernel: GN1 finish -> normalize tile -> K=256 GEMM -> q/k/v
// native layouts (unchanged, proven).
// ---------------------------------------------------------------------------
__global__ __launch_bounds__(256) void qkv_fused_kernel(
    const float* __restrict__ x_f, const float* __restrict__ part1p,
    const float* __restrict__ g1, const float* __restrict__ be1,
    const unsigned short* __restrict__ W, const float* __restrict__ qscale,
    unsigned short* __restrict__ qn, unsigned short* __restrict__ kn,
    unsigned short* __restrict__ vs) {
  int t = threadIdx.x;
  int w = t >> 6, lane = t & 63, l16 = lane & 15, quad = lane >> 4;
  int p0 = blockIdx.x * 16;
  int b = p0 >> 12;
  __shared__ float red[32][8][2];
  __shared__ float sm[32], si[32];
  {
    int g = t >> 3, seg = t & 7;
    float s = 0.f, s2 = 0.f;
    const float* pp = part1p + ((size_t)(b * 32 + g) * 128 + seg * 16) * 2;
#pragma unroll
    for (int k = 0; k < 16; ++k) { s += pp[k * 2]; s2 += pp[k * 2 + 1]; }
    red[g][seg][0] = s; red[g][seg][1] = s2;
  }
  __syncthreads();
  if (t < 32) {
    float s = 0.f, s2 = 0.f;
#pragma unroll
    for (int k = 0; k < 8; ++k) { s += red[t][k][0]; s2 += red[t][k][1]; }
    float mean = s * (1.f / 32768.f);
    float var = s2 * (1.f / 32768.f) - mean * mean;
    sm[t] = mean; si[t] = rsqrtf(var + GEPS);
  }
  __syncthreads();
  __shared__ unsigned short Ys[16][264];
  {
    int p = t & 15, cg = t >> 4;
    int n = (p0 & 4095) + p;
    const float* src = x_f + ((size_t)b * NC + cg * 16) * NPIX + n;
    U16x8 lo, hi;
#pragma unroll
    for (int cc = 0; cc < 16; ++cc) {
      int c = cg * 16 + cc;
      int g = c >> 3;
      float gg = g1[c] * si[g];
      float vv = (src[(size_t)cc * NPIX] - sm[g]) * gg + be1[c];
      if (cc < 8) lo.us[cc] = tobf(vv); else hi.us[cc - 8] = tobf(vv);
    }
    *(uint4*)&Ys[p][cg * 16] = lo.u4;
    *(uint4*)&Ys[p][cg * 16 + 8] = hi.u4;
  }
  __syncthreads();
  int ob = blockIdx.y * 384 + w * 96;
  f32x4 acc[6] = {};
#pragma unroll
  for (int k0 = 0; k0 < 256; k0 += 32) {
    U16x8 bfr; bfr.u4 = *(const uint4*)&Ys[l16][k0 + quad * 8];
#pragma unroll
    for (int ot = 0; ot < 6; ++ot) {
      U16x8 af;
      af.u4 = *(const uint4*)(W + (size_t)(ob + ot * 16 + l16) * 256 + k0 + quad * 8);
      acc[ot] = __builtin_amdgcn_mfma_f32_16x16x32_bf16(af.v, bfr.v, acc[ot], 0, 0, 0);
    }
  }
  int n = (p0 & 4095) + l16;
#pragma unroll
  for (int ot = 0; ot < 6; ++ot) {
    int oc = ob + ot * 16 + quad * 4;
    float v[4];
#pragma unroll
    for (int r = 0; r < 4; ++r) v[r] = acc[ot][r] * qscale[oc + r];
    int sec = oc >> 8;
    int c = oc & 255;
    if (sec < 2) {
      int hh = c >> 5, d = c & 31;
      unsigned short* base = sec == 0 ? qn : kn;
      uint2 pk;
      pk.x = (unsigned)tobf(v[0]) | ((unsigned)tobf(v[1]) << 16);
      pk.y = (unsigned)tobf(v[2]) | ((unsigned)tobf(v[3]) << 16);
      *(uint2*)(base + ((size_t)(b * NHEAD + hh) * NPIX + n) * HD + d) = pk;
    } else {
#pragma unroll
      for (int r = 0; r < 4; ++r)
        vs[((size_t)(b * NC + c + r)) * NPIX + n] = tobf(v[r]);
    }
  }
}

// ---------------------------------------------------------------------------
// MFMA flash attention v9 (proven, unchanged): cooperative DMA staging,
// 2 barriers/iter, 128-query blocks (512 thr / 8 waves).
// ---------------------------------------------------------------------------
__global__ __launch_bounds__(512) void attn9_kernel(
    const unsigned short* __restrict__ qn, const unsigned short* __restrict__ kn,
    const unsigned short* __restrict__ vs, float* __restrict__ pO,
    float* __restrict__ pl) {
  int bx = blockIdx.x;
  int iblk = bx & 31, chunk = bx >> 5;
  int i0 = iblk * 128;
  int jbase = chunk * JLEN;
  int h = blockIdx.y, b = blockIdx.z;
  int bh = b * NHEAD + h;
  int t = threadIdx.x;
  int w = t >> 6, lane = t & 63, l16 = lane & 15, quad = lane >> 4;

  __shared__ unsigned short Kt[2048];      // [64 j][4 p][8] swizzled
  __shared__ unsigned short Vt[2048];      // [32 d][8 p][8] swizzled
  __shared__ unsigned short Pl[8][16][72];

  U16x8 qf;
  qf.u4 = *(const uint4*)(qn + ((size_t)bh * NPIX + i0 + w * 16 + l16) * HD + quad * 8);
  U16x8 ones;
#pragma unroll
  for (int j = 0; j < 8; ++j) ones.us[j] = 0x3F80;

  const unsigned short* gp;
  lds_u32* dst;
  if (w < 4) {
    int kj = (w << 4) + (lane >> 2);
    int kg = (lane & 3) ^ ((kj >> 1) & 3);
    gp = kn + ((size_t)bh * NPIX + jbase + kj) * HD + kg * 8;
    dst = (lds_u32*)&Kt[w * 512];
  } else {
    int vd = ((w - 4) << 3) + (lane >> 3);
    int vg = (lane & 7) ^ (vd & 7);
    gp = vs + ((size_t)(b * NC + h * HD + vd)) * NPIX + jbase + vg * 8;
    dst = (lds_u32*)&Vt[(w - 4) * 512];
  }
  int gstep = (w < 4) ? 64 * HD : 64;

  f32x4 o0 = {0.f, 0.f, 0.f, 0.f}, o1 = {0.f, 0.f, 0.f, 0.f};
  f32x4 lacc = {0.f, 0.f, 0.f, 0.f};
  const f32x4 zf = {0.f, 0.f, 0.f, 0.f};

  int sp = (quad ^ ((l16 >> 1) & 3)) * 8;
  for (int jt = 0; jt < JLEN; jt += 64) {
    __builtin_amdgcn_global_load_lds((glb_u32*)gp, dst, 16, 0, 0);
    gp += gstep;
    __syncthreads();   // drains DMA (vmcnt0) + all waves staged
    f32x4 st[4];
#pragma unroll
    for (int jj = 0; jj < 4; ++jj) {
      U16x8 kf; kf.u4 = *(const uint4*)&Kt[(jj * 16 + l16) * 32 + sp];
      st[jj] = __builtin_amdgcn_mfma_f32_16x16x32_bf16(kf.v, qf.v, zf, 0, 0, 0);
    }
#pragma unroll
    for (int jj = 0; jj < 4; ++jj) {
      uint2 pk;
      pk.x = packtrunc(__builtin_amdgcn_exp2f(st[jj][0]), __builtin_amdgcn_exp2f(st[jj][1]));
      pk.y = packtrunc(__builtin_amdgcn_exp2f(st[jj][2]), __builtin_amdgcn_exp2f(st[jj][3]));
      *(uint2*)&Pl[w][l16][jj * 16 + quad * 4] = pk;
    }
#pragma unroll
    for (int ks = 0; ks < 2; ++ks) {
      U16x8 pb; pb.u4 = *(const uint4*)&Pl[w][l16][ks * 32 + quad * 8];
      int vp = ((ks * 4 + quad) ^ (l16 & 7)) * 8;
      U16x8 va; va.u4 = *(const uint4*)&Vt[l16 * 64 + vp];
      U16x8 vb2; vb2.u4 = *(const uint4*)&Vt[(16 + l16) * 64 + vp];
      o0 = __builtin_amdgcn_mfma_f32_16x16x32_bf16(va.v, pb.v, o0, 0, 0, 0);
      o1 = __builtin_amdgcn_mfma_f32_16x16x32_bf16(vb2.v, pb.v, o1, 0, 0, 0);
      lacc = __builtin_amdgcn_mfma_f32_16x16x32_bf16(ones.v, pb.v, lacc, 0, 0, 0);
    }
    __syncthreads();   // all waves done reading Kt/Vt before next DMA
  }

  int pr = bh * 64 + iblk * 2 + (w >> 2);
  float* ob = pO + ((size_t)chunk * 1024 + pr) * 2048;
  int icol = (w & 3) * 16 + l16;
#pragma unroll
  for (int r = 0; r < 4; ++r) {
    ob[(quad * 4 + r) * 64 + icol] = o0[r];
    ob[(16 + quad * 4 + r) * 64 + icol] = o1[r];
  }
  if (quad == 0)
    pl[((size_t)chunk * 1024 + pr) * 64 + icol] = lacc[0];
}

// ---------------------------------------------------------------------------
// wout GEMM with INLINE combine (r11 single-launch structure restored: the
// r12/r13 channel-split DUPLICATED the combine -> net loss). Epilogue now
// writes xres PIXEL-MAJOR [p][256] fp32: C-layout gives each lane 4
// consecutive channels for fixed pixel -> 16 B/lane fully coalesced stores.
// Residual x read stays channel-major (x_f layout is input-dictated).
// Also emits per-block GN2 partials (layout-agnostic sums).
// ---------------------------------------------------------------------------
__global__ __launch_bounds__(256) void wout_kernel(
    const unsigned short* __restrict__ W, const float* __restrict__ pO,
    const float* __restrict__ pl, const float* __restrict__ bias,
    const float* __restrict__ res, float* __restrict__ xres_t,
    float* __restrict__ part2p) {
  int t = threadIdx.x;
  int w = t >> 6, lane = t & 63, l16 = lane & 15, quad = lane >> 4;
  int p = blockIdx.x * 16 + l16;
  int b = p >> 12, n = p & 4095;
  int i = p & 63, iblk = (p >> 6) & 63;
  int ob = w * 64;
  float rinv8[8];
#pragma unroll
  for (int hh = 0; hh < 8; ++hh) {
    size_t pr = (size_t)(b * NHEAD + hh) * 64 + iblk;
    float l = pl[pr * 64 + i] + pl[(1024 + pr) * 64 + i];
    rinv8[hh] = 1.f / l;
  }
  f32x4 acc[4] = {};
#pragma unroll
  for (int k0 = 0; k0 < 256; k0 += 32) {
    int hh = k0 >> 5;
    const float* q0 = pO + ((size_t)(b * NHEAD + hh) * 64 + iblk) * 2048 + quad * 8 * 64 + i;
    const float* q1 = q0 + (size_t)1024 * 2048;
    float rv = rinv8[hh];
    U16x8 bfr;
#pragma unroll
    for (int u = 0; u < 4; ++u) {
      float va = (q0[(2 * u) * 64] + q1[(2 * u) * 64]) * rv;
      float vb = (q0[(2 * u + 1) * 64] + q1[(2 * u + 1) * 64]) * rv;
      bfr.u32[u] = packtrunc(va, vb);
    }
#pragma unroll
    for (int ot = 0; ot < 4; ++ot) {
      U16x8 af;
      af.u4 = *(const uint4*)(W + (size_t)(ob + ot * 16 + l16) * 256 + k0 + quad * 8);
      acc[ot] = __builtin_amdgcn_mfma_f32_16x16x32_bf16(af.v, bfr.v, acc[ot], 0, 0, 0);
    }
  }
  __shared__ float sb[256][4][2];
#pragma unroll
  for (int ot = 0; ot < 4; ++ot) {
    int oc = ob + ot * 16 + quad * 4;
    float s = 0.f, s2 = 0.f;
    float v4[4];
#pragma unroll
    for (int r = 0; r < 4; ++r) {
      float vv = acc[ot][r] + bias[oc + r] + res[((size_t)(b * NC + oc + r)) * NPIX + n];
      v4[r] = vv;
      s += vv; s2 += vv * vv;
    }
    *(float4*)&xres_t[(size_t)p * NC + oc] = make_float4(v4[0], v4[1], v4[2], v4[3]);
    sb[t][ot][0] = s; sb[t][ot][1] = s2;
  }
  __syncthreads();
  if (t < 32) {  // group g == t; channels [g*8, g*8+8)
    int ww = t >> 3, rem = t & 7, ot = rem >> 1, qp = rem & 1;
    float s = 0.f, s2 = 0.f;
#pragma unroll
    for (int q = 2 * qp; q < 2 * qp + 2; ++q)
      for (int l = 0; l < 16; ++l) {
        int tt = ww * 64 + q * 16 + l;
        s += sb[tt][ot][0]; s2 += sb[tt][ot][1];
      }
    size_t idx = ((size_t)(b * 32 + t) * 256 + (blockIdx.x & 255)) * 2;
    part2p[idx] = s; part2p[idx + 1] = s2;
  }
}

// ---------------------------------------------------------------------------
// MLP mega-kernel: xres now PIXEL-MAJOR -> normalize phase remapped
// (p = t>>4, cg = t&15) so 16 consecutive threads read a contiguous 1 KB
// row (fully coalesced fp32). Rest unchanged.
// ---------------------------------------------------------------------------
__global__ __launch_bounds__(256) void mlp_fused_kernel(
    const void* __restrict__ xraw, const float* __restrict__ xres_t,
    const float* __restrict__ part2p, const float* __restrict__ g2,
    const float* __restrict__ be2, const unsigned short* __restrict__ W1,
    const float* __restrict__ b1, const unsigned short* __restrict__ W2,
    const float* __restrict__ b2, void* __restrict__ dout) {
  int wbf = detect_bf(xraw);
  int t = threadIdx.x;
  int w = t >> 6, lane = t & 63, l16 = lane & 15, quad = lane >> 4;
  int p0 = blockIdx.x * 16;
  int b = p0 >> 12;
  __shared__ float red[32][8][2];
  __shared__ float sm[32], si[32];
  {
    int g = t >> 3, seg = t & 7;
    float s = 0.f, s2 = 0.f;
    const float* pp = part2p + ((size_t)(b * 32 + g) * 256 + seg * 32) * 2;
#pragma unroll
    for (int k = 0; k < 32; ++k) { s += pp[k * 2]; s2 += pp[k * 2 + 1]; }
    red[g][seg][0] = s; red[g][seg][1] = s2;
  }
  __syncthreads();
  if (t < 32) {
    float s = 0.f, s2 = 0.f;
#pragma unroll
    for (int k = 0; k < 8; ++k) { s += red[t][k][0]; s2 += red[t][k][1]; }
    float mean = s * (1.f / 32768.f);
    float var = s2 * (1.f / 32768.f) - mean * mean;
    sm[t] = mean; si[t] = rsqrtf(var + GEPS);
  }
  __syncthreads();
  __shared__ float Xs[16][261];
  __shared__ unsigned short Ys[16][264];
  {
    int p = t >> 4, cg = t & 15;  // coalesced: 16 consecutive t span one row
    const float* src = xres_t + (size_t)(p0 + p) * NC + cg * 16;
    U16x8 lo, hi;
#pragma unroll
    for (int cc = 0; cc < 16; ++cc) {
      int c = cg * 16 + cc;
      int g = c >> 3;
      float v = src[cc];
      Xs[p][c] = v;
      float yv = (v - sm[g]) * (g2[c] * si[g]) + be2[c];
      if (cc < 8) lo.us[cc] = tobf(yv); else hi.us[cc - 8] = tobf(yv);
    }
    *(uint4*)&Ys[p][cg * 16] = lo.u4;
    *(uint4*)&Ys[p][cg * 16 + 8] = hi.u4;
  }
  __syncthreads();
  f32x4 a1 = {0.f, 0.f, 0.f, 0.f};
#pragma unroll
  for (int k0 = 0; k0 < 256; k0 += 32) {
    U16x8 bfr; bfr.u4 = *(const uint4*)&Ys[l16][k0 + quad * 8];
    U16x8 af;
    af.u4 = *(const uint4*)(W1 + (size_t)(w * 16 + l16) * 256 + k0 + quad * 8);
    a1 = __builtin_amdgcn_mfma_f32_16x16x32_bf16(af.v, bfr.v, a1, 0, 0, 0);
  }
  __shared__ unsigned short Hs[16][72];
  {
    int oc = w * 16 + quad * 4;
    float h0 = geluf(a1[0] + b1[oc]),     h1 = geluf(a1[1] + b1[oc + 1]);
    float h2 = geluf(a1[2] + b1[oc + 2]), h3 = geluf(a1[3] + b1[oc + 3]);
    uint2 pk;
    pk.x = (unsigned)tobf(h0) | ((unsigned)tobf(h1) << 16);
    pk.y = (unsigned)tobf(h2) | ((unsigned)tobf(h3) << 16);
    *(uint2*)&Hs[l16][oc] = pk;
  }
  __syncthreads();
  f32x4 a2[4] = {};
#pragma unroll
  for (int k0 = 0; k0 < 64; k0 += 32) {
    U16x8 bfr; bfr.u4 = *(const uint4*)&Hs[l16][k0 + quad * 8];
#pragma unroll
    for (int ot = 0; ot < 4; ++ot) {
      U16x8 af;
      af.u4 = *(const uint4*)(W2 + (size_t)(w * 64 + ot * 16 + l16) * 64 + k0 + quad * 8);
      a2[ot] = __builtin_amdgcn_mfma_f32_16x16x32_bf16(af.v, bfr.v, a2[ot], 0, 0, 0);
    }
  }
  int n = (p0 & 4095) + l16;
#pragma unroll
  for (int ot = 0; ot < 4; ++ot) {
    int oc = w * 64 + ot * 16 + quad * 4;
#pragma unroll
    for (int r = 0; r < 4; ++r) {
      float v = a2[ot][r] + b2[oc + r] + Xs[l16][oc + r];
      size_t oidx = ((size_t)(b * NC + oc + r)) * NPIX + n;
      if (wbf) ((__hip_bfloat16*)dout)[oidx] = __float2bfloat16(v);
      else ((float*)dout)[oidx] = v;
    }
  }
}

// ---------------------------------------------------------------------------
// Launch pipeline: 5 kernels.
// ---------------------------------------------------------------------------
extern "C" void kernel_launch(void* const* d_in, const int* in_sizes, int n_in,
                              void* d_out, int out_size, void* d_ws, size_t ws_size,
                              hipStream_t stream) {
  float* ws = (float*)d_ws;
  size_t off = 16;
  float* x_f    = ws + off; off += (size_t)NB * NC * NPIX;
  float* wqkv_f = ws + off; off += 768 * 256;
  float* wout_f = ws + off; off += 256 * 256;
  float* bout_f = ws + off; off += 256;
  float* temp_f = ws + off; off += 8;
  float* g1_f   = ws + off; off += 256;
  float* be1_f  = ws + off; off += 256;
  float* g2_f   = ws + off; off += 256;
  float* be2_f  = ws + off; off += 256;
  float* wm1_f  = ws + off; off += 64 * 256;
  float* bm1_f  = ws + off; off += 64;
  float* wm2_f  = ws + off; off += 256 * 64;
  float* bm2_f  = ws + off; off += 256;
  float* xres   = ws + off; off += (size_t)NB * NC * NPIX;  // pixel-major [8192][256]
  unsigned short* qn     = (unsigned short*)(ws + off); off += 1048576;  // [16][4096][32]
  unsigned short* kn     = (unsigned short*)(ws + off); off += 1048576;  // [16][4096][32]
  unsigned short* vs     = (unsigned short*)(ws + off); off += 1048576;  // [2][256][4096]
  unsigned short* wqkv_b = (unsigned short*)(ws + off); off += 98304;
  unsigned short* wout_b = (unsigned short*)(ws + off); off += 32768;
  unsigned short* wm1_b  = (unsigned short*)(ws + off); off += 8192;
  unsigned short* wm2_b  = (unsigned short*)(ws + off); off += 8192;
  float* qscale = ws + off; off += 768;
  float* part1p = ws + off; off += 16384;   // [8192][2] GN1 block partials
  float* part2p = ws + off; off += 65536;   // [64 bg][256 blk][2] GN2 partials
  float* pO     = ws + off; off += (size_t)NCHUNK * 1024 * 2048;
  float* plb    = ws + off; off += (size_t)NCHUNK * 1024 * 64;
  (void)wqkv_f; (void)wout_f; (void)wm1_f; (void)wm2_f; (void)temp_f; (void)bm1_f;

  ConvArgs ca;
  int acc = 0;
  for (int i = 0; i < 13; ++i) {
    ca.src[i] = d_in[i];
    ca.off[i] = acc;
    acc += (i < n_in) ? in_sizes[i] : 0;
  }
  ca.off[13] = acc;
  conv_prep_kernel<<<(acc + 255) / 256, 256, 0, stream>>>(
      ca, x_f, acc, wqkv_b, wout_b, wm1_b, wm2_b, qscale, part1p);

  qkv_fused_kernel<<<dim3(512, 2), 256, 0, stream>>>(
      x_f, part1p, g1_f, be1_f, wqkv_b, qscale, qn, kn, vs);

  attn9_kernel<<<dim3(32 * NCHUNK, NHEAD, NB), 512, 0, stream>>>(qn, kn, vs, pO, plb);

  wout_kernel<<<512, 256, 0, stream>>>(wout_b, pO, plb, bout_f, x_f, xres, part2p);

  mlp_fused_kernel<<<512, 256, 0, stream>>>(
      d_in[0], xres, part2p, g2_f, be2_f, wm1_b, bm1_f, wm2_b, bm2_f, d_out);
}